// Round 9
// baseline (1544.299 us; speedup 1.0000x reference)
//
#include <hip/hip_runtime.h>
#include <math.h>

// Problem constants (uniform scenes per reference)
#define NB 768      // batch = S*P
#define NS 32       // scenes
#define NP 24       // peds/scene
#define ED 64       // embedding dim E
#define HD 128      // hidden H
#define G4 512      // 4*H
#define BNKD 1024   // bottleneck
#define KM1 1152    // H + BNK
#define TSTEPS 12
#define AR 2        // rows per step_a block (grid 384 -> 6 waves/CU)
#define BPITCH 516  // pool B LDS row pitch in shorts (1032B -> conflict-free)

typedef __bf16 bf16x8 __attribute__((ext_vector_type(8)));
typedef float f32x4 __attribute__((ext_vector_type(4)));
typedef unsigned short u16x8 __attribute__((ext_vector_type(8)));

__device__ __forceinline__ unsigned short f2bf(float f) {
  unsigned u = __float_as_uint(f);
  u = (u + 0x7FFFu + ((u >> 16) & 1u)) >> 16;   // RNE
  return (unsigned short)u;
}
__device__ __forceinline__ unsigned pack2bf(float a, float b) {
  return (unsigned)f2bf(a) | ((unsigned)f2bf(b) << 16);
}
__device__ __forceinline__ float bf2f(unsigned short h) {
  return __uint_as_float(((unsigned)h) << 16);
}

// ---------------------------------------------------------------------------
// init: carries, dec_in0, folded pool-L1 weights (Wc = W_pse@W_p1[:64], bc),
// bf16-transposed W2T[n][k]=W_p2[k][n], W1T[n][k]=W_m1[k][n], WmT[n][k]=W_m2[k][n]
// ---------------------------------------------------------------------------
__global__ void init_kernel(const float* __restrict__ last_pos,
                            const float* __restrict__ last_pos_rel,
                            const float* __restrict__ c0,
                            const float* __restrict__ W_se,
                            const float* __restrict__ b_se,
                            const float* __restrict__ W_pse,
                            const float* __restrict__ b_pse,
                            const float* __restrict__ W_p1,
                            const float* __restrict__ b_p1,
                            const float* __restrict__ W_p2,
                            const float* __restrict__ W_m1,
                            const float* __restrict__ W_m2,
                            float* __restrict__ ccar,
                            float* __restrict__ din, float* __restrict__ lpos,
                            float* __restrict__ Wc, float* __restrict__ bc,
                            unsigned short* __restrict__ W2T,
                            unsigned short* __restrict__ W1T,
                            unsigned short* __restrict__ WmT) {
  int stride = gridDim.x * blockDim.x;
  int idx0 = blockIdx.x * blockDim.x + threadIdx.x;
  for (int i = idx0; i < NB * HD; i += stride) ccar[i] = c0[i];
  for (int i = idx0; i < NB * 2; i += stride) lpos[i] = last_pos[i];
  for (int i = idx0; i < NB * ED; i += stride) {
    int r = i >> 6, e = i & 63;
    din[i] = b_se[e] + last_pos_rel[2 * r] * W_se[e]
                     + last_pos_rel[2 * r + 1] * W_se[ED + e];
  }
  for (int n = idx0; n < G4; n += stride) {
    float w0 = 0.f, w1 = 0.f, bb = b_p1[n];
    for (int e = 0; e < ED; ++e) {
      float wp = W_p1[e * G4 + n];
      w0 += W_pse[e] * wp;
      w1 += W_pse[ED + e] * wp;
      bb += b_pse[e] * wp;
    }
    Wc[n] = w0; Wc[G4 + n] = w1; bc[n] = bb;
  }
  // W2T: 1024 n x 512 k bf16
  for (int idx = idx0; idx < 1024 * 64; idx += stride) {
    int n = idx & 1023, k0 = (idx >> 10) << 3;
    unsigned pk0 = pack2bf(W_p2[(k0 + 0) * BNKD + n], W_p2[(k0 + 1) * BNKD + n]);
    unsigned pk1 = pack2bf(W_p2[(k0 + 2) * BNKD + n], W_p2[(k0 + 3) * BNKD + n]);
    unsigned pk2 = pack2bf(W_p2[(k0 + 4) * BNKD + n], W_p2[(k0 + 5) * BNKD + n]);
    unsigned pk3 = pack2bf(W_p2[(k0 + 6) * BNKD + n], W_p2[(k0 + 7) * BNKD + n]);
    *(uint4*)&W2T[n * G4 + k0] = make_uint4(pk0, pk1, pk2, pk3);
  }
  // W1T: 1024 n x 1152 k bf16
  for (int idx = idx0; idx < 1024 * 144; idx += stride) {
    int n = idx & 1023, k0 = (idx >> 10) << 3;
    unsigned pk0 = pack2bf(W_m1[(k0 + 0) * BNKD + n], W_m1[(k0 + 1) * BNKD + n]);
    unsigned pk1 = pack2bf(W_m1[(k0 + 2) * BNKD + n], W_m1[(k0 + 3) * BNKD + n]);
    unsigned pk2 = pack2bf(W_m1[(k0 + 4) * BNKD + n], W_m1[(k0 + 5) * BNKD + n]);
    unsigned pk3 = pack2bf(W_m1[(k0 + 6) * BNKD + n], W_m1[(k0 + 7) * BNKD + n]);
    *(uint4*)&W1T[n * KM1 + k0] = make_uint4(pk0, pk1, pk2, pk3);
  }
  // WmT: 128 n x 1024 k bf16   (W_m2 is [1024][128])
  for (int idx = idx0; idx < 128 * 128; idx += stride) {
    int n = idx & 127, k0 = (idx >> 7) << 3;
    unsigned pk0 = pack2bf(W_m2[(k0 + 0) * HD + n], W_m2[(k0 + 1) * HD + n]);
    unsigned pk1 = pack2bf(W_m2[(k0 + 2) * HD + n], W_m2[(k0 + 3) * HD + n]);
    unsigned pk2 = pack2bf(W_m2[(k0 + 4) * HD + n], W_m2[(k0 + 5) * HD + n]);
    unsigned pk3 = pack2bf(W_m2[(k0 + 6) * HD + n], W_m2[(k0 + 7) * HD + n]);
    *(uint4*)&WmT[n * BNKD + k0] = make_uint4(pk0, pk1, pk2, pk3);
  }
}

// ---------------------------------------------------------------------------
// step A: LSTM cell (h read = relu(hacc_prev) unless first step) + rel/curr pos
// + dec_in_next + Hp1 = h_new @ W_p1[64:] + bc + hacc_next init = b_m2.
// h_new also written bf16 into mhA cols 0..127. 2 rows/block, grid 384.
// ---------------------------------------------------------------------------
__global__ __launch_bounds__(256) void step_a(
    const float* __restrict__ hprev, const float* __restrict__ cprev,
    const float* __restrict__ din, const float* __restrict__ lpos_in,
    const float* __restrict__ W_ih, const float* __restrict__ b_ih,
    const float* __restrict__ W_hh, const float* __restrict__ b_hh,
    const float* __restrict__ W_hp, const float* __restrict__ b_hp,
    const float* __restrict__ W_se, const float* __restrict__ b_se,
    const float* __restrict__ W_p1, const float* __restrict__ bc,
    const float* __restrict__ b_m2,
    unsigned short* __restrict__ mhA, float* __restrict__ cnext,
    float* __restrict__ dnext, float* __restrict__ lpos_out,
    float* __restrict__ Hp1, float* __restrict__ pred_out,
    float* __restrict__ hacc_next, int relu_in) {
  __shared__ float x[AR][192];   // [din(64) | h(128)]
  __shared__ float gg[AR][G4];
  __shared__ float hl[AR][HD];
  __shared__ float rp[AR][2];
  int t = threadIdx.x;
  int r0 = blockIdx.x * AR;

  for (int i = t; i < AR * ED; i += 256) { int r = i >> 6, k = i & 63; x[r][k] = din[(r0 + r) * ED + k]; }
  for (int i = t; i < AR * HD; i += 256) {
    int r = i >> 7, k = i & 127;
    float v = hprev[(r0 + r) * HD + k];
    if (relu_in) v = fmaxf(v, 0.f);
    x[r][ED + k] = v;
    hacc_next[(r0 + r) * HD + k] = b_m2[k];   // bias-init mlp2 accumulator
  }
  __syncthreads();

  float acc[AR][2];
#pragma unroll
  for (int r = 0; r < AR; ++r) { acc[r][0] = b_ih[t] + b_hh[t]; acc[r][1] = b_ih[t + 256] + b_hh[t + 256]; }
#pragma unroll 4
  for (int k = 0; k < ED; ++k) {
    float w0 = W_ih[k * G4 + t], w1 = W_ih[k * G4 + t + 256];
#pragma unroll
    for (int r = 0; r < AR; ++r) { float a = x[r][k]; acc[r][0] += a * w0; acc[r][1] += a * w1; }
  }
#pragma unroll 4
  for (int k = 0; k < HD; ++k) {
    float w0 = W_hh[k * G4 + t], w1 = W_hh[k * G4 + t + 256];
#pragma unroll
    for (int r = 0; r < AR; ++r) { float a = x[r][ED + k]; acc[r][0] += a * w0; acc[r][1] += a * w1; }
  }
#pragma unroll
  for (int r = 0; r < AR; ++r) { gg[r][t] = acc[r][0]; gg[r][t + 256] = acc[r][1]; }
  __syncthreads();

  for (int i = t; i < AR * HD; i += 256) {
    int r = i >> 7, k = i & 127;
    float ig = gg[r][k], fg = gg[r][HD + k], gz = gg[r][2 * HD + k], og = gg[r][3 * HD + k];
    float si = 1.f / (1.f + expf(-ig));
    float sf = 1.f / (1.f + expf(-fg));
    float so = 1.f / (1.f + expf(-og));
    float gt = tanhf(gz);
    float c = sf * cprev[(r0 + r) * HD + k] + si * gt;
    float h = so * tanhf(c);
    cnext[(r0 + r) * HD + k] = c;
    mhA[(size_t)(r0 + r) * KM1 + k] = f2bf(h);
    hl[r][k] = h;
  }
  __syncthreads();

  if (t < AR * 2) {
    int r = t >> 1, d = t & 1;
    float s = b_hp[d];
    for (int k = 0; k < HD; ++k) s += hl[r][k] * W_hp[k * 2 + d];
    rp[r][d] = s;
    pred_out[(r0 + r) * 2 + d] = s;
    lpos_out[(r0 + r) * 2 + d] = s + lpos_in[(r0 + r) * 2 + d];
  }
  __syncthreads();

  for (int i = t; i < AR * ED; i += 256) {
    int r = i >> 6, e = i & 63;
    dnext[(r0 + r) * ED + e] = b_se[e] + rp[r][0] * W_se[e] + rp[r][1] * W_se[ED + e];
  }

  // Hp1 = h_new @ W_p1[64:192] + bc   (bc folded here)
  float bc0 = bc[t], bc1 = bc[t + 256];
  float acc2[AR][2];
#pragma unroll
  for (int r = 0; r < AR; ++r) { acc2[r][0] = bc0; acc2[r][1] = bc1; }
#pragma unroll 4
  for (int k = 0; k < HD; ++k) {
    float w0 = W_p1[(ED + k) * G4 + t], w1 = W_p1[(ED + k) * G4 + t + 256];
#pragma unroll
    for (int r = 0; r < AR; ++r) { float a = hl[r][k]; acc2[r][0] += a * w0; acc2[r][1] += a * w1; }
  }
#pragma unroll
  for (int r = 0; r < AR; ++r) {
    Hp1[(r0 + r) * G4 + t] = acc2[r][0];
    Hp1[(r0 + r) * G4 + t + 256] = acc2[r][1];
  }
}

// ---------------------------------------------------------------------------
// ygen: materialize Y[s][ip][48][512] bf16 once. XCD-affine: b = ip*32 + s,
// so scene s's blocks land on XCD s%8 -> Y slice (2.4MB/XCD) stays in that
// XCD's L2 (write-back, never spills to HBM; pool reads hit L2).
// ---------------------------------------------------------------------------
__global__ __launch_bounds__(256) void ygen(
    const float* __restrict__ curr_pos, const float* __restrict__ Hp1,
    const float* __restrict__ Wc, unsigned short* __restrict__ Y) {
  __shared__ float psx[NP], psy[NP];
  int t = threadIdx.x;
  int b = blockIdx.x;
  int s = b & 31, ip = b >> 5;     // scene -> XCD s%8
  if (t < NP) {
    psx[t] = curr_pos[(s * NP + t) * 2];
    psy[t] = curr_pos[(s * NP + t) * 2 + 1];
  }
  __syncthreads();
  unsigned short* yb = Y + (size_t)(s * 12 + ip) * 48 * G4;
  for (int idx = t; idx < 48 * 64; idx += 256) {
    int row = idx >> 6, kc = (idx & 63) << 3;
    int j = row % 24, g = row / 24;
    float rx = psx[j] - psx[ip * 2 + g];
    float ry = psy[j] - psy[ip * 2 + g];
    const float* hr = &Hp1[(size_t)(s * NP + j) * G4 + kc];
    float4 h0 = *(const float4*)hr;
    float4 h1 = *(const float4*)(hr + 4);
    float4 wx0 = *(const float4*)&Wc[kc];
    float4 wx1 = *(const float4*)&Wc[kc + 4];
    float4 wy0 = *(const float4*)&Wc[G4 + kc];
    float4 wy1 = *(const float4*)&Wc[G4 + kc + 4];
    uint4 pk;
    pk.x = pack2bf(fmaxf(h0.x + rx * wx0.x + ry * wy0.x, 0.f),
                   fmaxf(h0.y + rx * wx0.y + ry * wy0.y, 0.f));
    pk.y = pack2bf(fmaxf(h0.z + rx * wx0.z + ry * wy0.z, 0.f),
                   fmaxf(h0.w + rx * wx0.w + ry * wy0.w, 0.f));
    pk.z = pack2bf(fmaxf(h1.x + rx * wx1.x + ry * wy1.x, 0.f),
                   fmaxf(h1.y + rx * wx1.y + ry * wy1.y, 0.f));
    pk.w = pack2bf(fmaxf(h1.z + rx * wx1.z + ry * wy1.z, 0.f),
                   fmaxf(h1.w + rx * wx1.w + ry * wy1.w, 0.f));
    *(uint4*)&yb[row * G4 + kc] = pk;
  }
}

// ---------------------------------------------------------------------------
// pool_mfma v7: pure GEMM + max-epilogue. b = nt*32 + s (scene -> XCD s%8,
// same XCD as ygen wrote -> A-reads are L2 hits). 512 threads (8 waves);
// B tile LDS-resident; A direct bf16 loads from L2-hot Y. No k-loop barriers.
// ---------------------------------------------------------------------------
__global__ __launch_bounds__(512, 1) void pool_mfma(
    const unsigned short* __restrict__ Y,
    const unsigned short* __restrict__ W2T, const float* __restrict__ b_p2,
    unsigned short* __restrict__ mhA) {
  __shared__ __align__(16) unsigned short Bl[128 * BPITCH];   // 132096 B
  int t = threadIdx.x;
  int b = blockIdx.x;              // 256 = 8 ntiles * 32 scenes
  int s = b & 31, nt = b >> 5;     // scene -> XCD s%8
  int n0 = nt * 128;

  // stage B: 128 rows x 512 k (coalesced 16B)
  for (int idx = t; idx < 128 * 64; idx += 512) {
    int row = idx >> 6, ch = (idx & 63) << 3;
    *(uint4*)&Bl[row * BPITCH + ch] = *(const uint4*)&W2T[(size_t)(n0 + row) * G4 + ch];
  }
  __syncthreads();

  int lane = t & 63, wave = t >> 6;
  int wn = wave & 1, wg = wave >> 1;
  int arow = lane & 15, ak = (lane >> 4) * 8;
  int h = lane >> 4;

  int boff[4];
#pragma unroll
  for (int nf = 0; nf < 4; ++nf)
    boff[nf] = (wn * 64 + nf * 16 + arow) * BPITCH + ak;

  for (int c = 0; c < 3; ++c) {
    int ip = wg * 3 + c;               // i-pair 0..11
    const unsigned short* Ab = Y + (size_t)((s * 12 + ip) * 48) * G4;
    const unsigned short* ap0 = Ab + (arow) * G4 + ak;
    const unsigned short* ap1 = Ab + (16 + arow) * G4 + ak;
    const unsigned short* ap2 = Ab + (32 + arow) * G4 + ak;

    f32x4 acc[3][4];
#pragma unroll
    for (int f = 0; f < 3; ++f)
#pragma unroll
      for (int nf = 0; nf < 4; ++nf) acc[f][nf] = (f32x4){0.f, 0.f, 0.f, 0.f};

#pragma unroll 4
    for (int kt = 0; kt < 16; ++kt) {
      int k0 = kt * 32;
      bf16x8 a0 = *(const bf16x8*)(ap0 + k0);
      bf16x8 a1 = *(const bf16x8*)(ap1 + k0);
      bf16x8 a2 = *(const bf16x8*)(ap2 + k0);
      bf16x8 bfr[4];
#pragma unroll
      for (int nf = 0; nf < 4; ++nf) bfr[nf] = *(const bf16x8*)&Bl[boff[nf] + k0];
#pragma unroll
      for (int nf = 0; nf < 4; ++nf) {
        acc[0][nf] = __builtin_amdgcn_mfma_f32_16x16x32_bf16(a0, bfr[nf], acc[0][nf], 0, 0, 0);
        acc[1][nf] = __builtin_amdgcn_mfma_f32_16x16x32_bf16(a1, bfr[nf], acc[1][nf], 0, 0, 0);
        acc[2][nf] = __builtin_amdgcn_mfma_f32_16x16x32_bf16(a2, bfr[nf], acc[2][nf], 0, 0, 0);
      }
    }

    // epilogue: max over j per ped group. frag rows: f0=g0 j0-15,
    // f1 lo=g0 j16-23 / hi=g1 j0-7, f2=g1 j8-23. C: row=(lane>>4)*4+reg.
    int iA = s * NP + ip * 2;
#pragma unroll
    for (int nf = 0; nf < 4; ++nf) {
      f32x4 a0 = acc[0][nf], a1 = acc[1][nf], a2 = acc[2][nf];
      float v0 = fmaxf(fmaxf(a0[0], a0[1]), fmaxf(a0[2], a0[3]));
      float v1 = fmaxf(fmaxf(a1[0], a1[1]), fmaxf(a1[2], a1[3]));
      float v2 = fmaxf(fmaxf(a2[0], a2[1]), fmaxf(a2[2], a2[3]));
      v0 = fmaxf(v0, __shfl_xor(v0, 16));
      v1 = fmaxf(v1, __shfl_xor(v1, 16));
      v2 = fmaxf(v2, __shfl_xor(v2, 16));
      float xx = (h < 2) ? fmaxf(v0, v1) : v0;    // g0 = f0 all + f1 lo
      xx = fmaxf(xx, __shfl_xor(xx, 32));
      float yy = (h >= 2) ? fmaxf(v2, v1) : v2;   // g1 = f1 hi + f2 all
      yy = fmaxf(yy, __shfl_xor(yy, 32));
      int col = n0 + wn * 64 + nf * 16 + (lane & 15);
      float bb = b_p2[col];
      xx = fmaxf(xx + bb, 0.f);
      yy = fmaxf(yy + bb, 0.f);
      if (h == 0) mhA[(size_t)iA * KM1 + HD + col] = f2bf(xx);
      if (h == 1) mhA[((size_t)iA + 1) * KM1 + HD + col] = f2bf(yy);
    }
  }
}

// ---------------------------------------------------------------------------
// mlp1_fused: stage1 mh_tile = relu(mhA @ W_m1 + b_m1) (32x128, regs; A is
// bf16 direct from mhA), stage2 hacc += mh_tile @ W_m2[n0:n0+128,:] via
// bf16 hi+lo MFMA + atomicAdd.
// ---------------------------------------------------------------------------
__global__ __launch_bounds__(256) void mlp1_fused(
    const unsigned short* __restrict__ mhA,
    const unsigned short* __restrict__ W1T, const float* __restrict__ b_m1,
    const unsigned short* __restrict__ WmT, float* __restrict__ hacc) {
  __shared__ __align__(16) float Pl[32][132];
  int t = threadIdx.x, b = blockIdx.x;   // 192 = 24 mt * 8 nt
  int mt = b >> 3, nt = b & 7;
  int r0 = mt * 32, n0 = nt * 128;
  int lane = t & 63, wid = t >> 6, wm = wid >> 1, wn = wid & 1;
  int arow = lane & 15, ak = (lane >> 4) * 8;
  int h = lane >> 4;

  f32x4 acc0[4];
#pragma unroll
  for (int nf = 0; nf < 4; ++nf) acc0[nf] = (f32x4){0.f, 0.f, 0.f, 0.f};
  int mrow = r0 + wm * 16 + arow;
  const unsigned short* bp[4];
#pragma unroll
  for (int nf = 0; nf < 4; ++nf)
    bp[nf] = W1T + (size_t)(n0 + wn * 64 + nf * 16 + arow) * KM1 + ak;
  const unsigned short* arow_m = mhA + (size_t)mrow * KM1 + ak;

#pragma unroll 4
  for (int kt = 0; kt < 36; ++kt) {
    bf16x8 a = *(const bf16x8*)(arow_m + kt * 32);
#pragma unroll
    for (int nf = 0; nf < 4; ++nf) {
      bf16x8 bb = *(const bf16x8*)(bp[nf] + kt * 32);
      acc0[nf] = __builtin_amdgcn_mfma_f32_16x16x32_bf16(a, bb, acc0[nf], 0, 0, 0);
    }
  }

  // P = relu(acc0 + b_m1) -> LDS (fp32)
#pragma unroll
  for (int nf = 0; nf < 4; ++nf) {
    int colp = wn * 64 + nf * 16 + arow;
    float bb = b_m1[n0 + colp];
#pragma unroll
    for (int rr = 0; rr < 4; ++rr)
      Pl[wm * 16 + h * 4 + rr][colp] = fmaxf(acc0[nf][rr] + bb, 0.f);
  }
  __syncthreads();

  // stage 2: (32x128 P-tile) @ WmT[:, n0:n0+128]^T -> 32x128 partial of h
  f32x4 acc2[4];
#pragma unroll
  for (int nf = 0; nf < 4; ++nf) acc2[nf] = (f32x4){0.f, 0.f, 0.f, 0.f};
  const unsigned short* b2p[4];
#pragma unroll
  for (int nf = 0; nf < 4; ++nf)
    b2p[nf] = WmT + (size_t)(wn * 64 + nf * 16 + arow) * BNKD + n0 + ak;
  const float* prow = &Pl[wm * 16 + arow][0];

#pragma unroll
  for (int k2 = 0; k2 < 4; ++k2) {
    u16x8 uh, ul;
#pragma unroll
    for (int q = 0; q < 8; ++q) {
      float vv = prow[k2 * 32 + ak + q];
      unsigned short hh = f2bf(vv);
      uh[q] = hh;
      ul[q] = f2bf(vv - bf2f(hh));
    }
    bf16x8 ahi = __builtin_bit_cast(bf16x8, uh);
    bf16x8 alo = __builtin_bit_cast(bf16x8, ul);
#pragma unroll
    for (int nf = 0; nf < 4; ++nf) {
      bf16x8 bb = *(const bf16x8*)(b2p[nf] + k2 * 32);
      acc2[nf] = __builtin_amdgcn_mfma_f32_16x16x32_bf16(ahi, bb, acc2[nf], 0, 0, 0);
      acc2[nf] = __builtin_amdgcn_mfma_f32_16x16x32_bf16(alo, bb, acc2[nf], 0, 0, 0);
    }
  }
#pragma unroll
  for (int nf = 0; nf < 4; ++nf)
#pragma unroll
    for (int rr = 0; rr < 4; ++rr)
      atomicAdd(&hacc[(size_t)(r0 + wm * 16 + h * 4 + rr) * HD + wn * 64 + nf * 16 + arow],
                acc2[nf][rr]);
}

// ---------------------------------------------------------------------------
// final: h_fin = relu(hacc)
// ---------------------------------------------------------------------------
__global__ void final_h(const float* __restrict__ hacc, float* __restrict__ out) {
  int i = blockIdx.x * 256 + threadIdx.x;
  if (i < NB * HD) out[i] = fmaxf(hacc[i], 0.f);
}

// ---------------------------------------------------------------------------
extern "C" void kernel_launch(void* const* d_in, const int* in_sizes, int n_in,
                              void* d_out, int out_size, void* d_ws, size_t ws_size,
                              hipStream_t stream) {
  const float* last_pos     = (const float*)d_in[0];
  const float* last_pos_rel = (const float*)d_in[1];
  const float* h0   = (const float*)d_in[2];
  const float* c0   = (const float*)d_in[3];
  const float* W_se = (const float*)d_in[5];
  const float* b_se = (const float*)d_in[6];
  const float* W_ih = (const float*)d_in[7];
  const float* b_ih = (const float*)d_in[8];
  const float* W_hh = (const float*)d_in[9];
  const float* b_hh = (const float*)d_in[10];
  const float* W_hp = (const float*)d_in[11];
  const float* b_hp = (const float*)d_in[12];
  const float* W_pse = (const float*)d_in[13];
  const float* b_pse = (const float*)d_in[14];
  const float* W_p1 = (const float*)d_in[15];
  const float* b_p1 = (const float*)d_in[16];
  const float* W_p2 = (const float*)d_in[17];
  const float* b_p2 = (const float*)d_in[18];
  const float* W_m1 = (const float*)d_in[19];
  const float* b_m1 = (const float*)d_in[20];
  const float* W_m2 = (const float*)d_in[21];
  const float* b_m2 = (const float*)d_in[22];

  float* ws = (float*)d_ws;
  float* hacc[2]  = { ws,           ws + 98304 };
  float* ccar[2]  = { ws + 196608,  ws + 294912 };
  float* din[2]   = { ws + 393216,  ws + 442368 };
  float* lposb[2] = { ws + 491520,  ws + 493056 };
  float* Hp1  = ws + 494592;                               // 393216 floats
  float* Wc   = ws + 887808;                               // 1024
  float* bc   = ws + 888832;                               // 512
  unsigned short* W2T = (unsigned short*)(ws + 889344);    // 1024x512 bf16
  unsigned short* W1T = (unsigned short*)(ws + 1151488);   // 1024x1152 bf16
  unsigned short* WmT = (unsigned short*)(ws + 1741312);   // 128x1024 bf16
  unsigned short* mhA = (unsigned short*)(ws + 1806848);   // 768x1152 bf16
  unsigned short* Y   = (unsigned short*)(ws + 2249216);   // 32x12x48x512 bf16

  float* pred = (float*)d_out;

  init_kernel<<<128, 256, 0, stream>>>(last_pos, last_pos_rel, c0,
                                       W_se, b_se, W_pse, b_pse, W_p1, b_p1,
                                       W_p2, W_m1, W_m2,
                                       ccar[0], din[0], lposb[0],
                                       Wc, bc, W2T, W1T, WmT);

  for (int t = 0; t < TSTEPS; ++t) {
    int a = t & 1, b = (t + 1) & 1;
    step_a<<<NB / AR, 256, 0, stream>>>(
        t == 0 ? h0 : hacc[a], ccar[a], din[a], lposb[a],
        W_ih, b_ih, W_hh, b_hh, W_hp, b_hp, W_se, b_se, W_p1, bc, b_m2,
        mhA, ccar[b], din[b], lposb[b], Hp1, pred + t * NB * 2,
        hacc[b], t == 0 ? 0 : 1);
    ygen<<<NS * 12, 256, 0, stream>>>(lposb[b], Hp1, Wc, Y);
    pool_mfma<<<NS * 8, 512, 0, stream>>>(Y, W2T, b_p2, mhA);
    mlp1_fused<<<192, 256, 0, stream>>>(mhA, W1T, b_m1, WmT, hacc[b]);
  }

  final_h<<<384, 256, 0, stream>>>(hacc[0], (float*)d_out + TSTEPS * NB * 2);
}

// Round 10
// 1166.958 us; speedup vs baseline: 1.3234x; 1.3234x over previous
//
#include <hip/hip_runtime.h>
#include <math.h>

// Problem constants (uniform scenes per reference)
#define NB 768      // batch = S*P
#define NS 32       // scenes
#define NP 24       // peds/scene
#define ED 64       // embedding dim E
#define HD 128      // hidden H
#define G4 512      // 4*H
#define BNKD 1024   // bottleneck
#define KM1 1152    // H + BNK
#define KG 192      // E + H
#define TSTEPS 12
#define AR 4        // rows per step_a block (R4 config — AR=2 regressed)
#define BPITCH 516  // pool B LDS row pitch in shorts (1032B -> conflict-free)
#define HPITCH 516

typedef __bf16 bf16x8 __attribute__((ext_vector_type(8)));
typedef float f32x4 __attribute__((ext_vector_type(4)));
typedef unsigned short u16x8 __attribute__((ext_vector_type(8)));

__device__ __forceinline__ unsigned short f2bf(float f) {
  unsigned u = __float_as_uint(f);
  u = (u + 0x7FFFu + ((u >> 16) & 1u)) >> 16;   // RNE
  return (unsigned short)u;
}
__device__ __forceinline__ unsigned pack2bf(float a, float b) {
  return (unsigned)f2bf(a) | ((unsigned)f2bf(b) << 16);
}
__device__ __forceinline__ float bf2f(unsigned short h) {
  return __uint_as_float(((unsigned)h) << 16);
}

// ---------------------------------------------------------------------------
// init: carries, dec_in0, folded pool-L1 weights (Wc, bc), bf16 prepacks:
// W2T[n][k]=W_p2[k][n]; W1T[n][k]=W_m1[k][n]; WmT[n][k]=W_m2[k][n];
// Wgb[k][n] = [W_ih;W_hh] bf16 (k-major); Wp1b[k][n] = W_p1[64:] bf16.
// ---------------------------------------------------------------------------
__global__ void init_kernel(const float* __restrict__ last_pos,
                            const float* __restrict__ last_pos_rel,
                            const float* __restrict__ c0,
                            const float* __restrict__ W_se,
                            const float* __restrict__ b_se,
                            const float* __restrict__ W_pse,
                            const float* __restrict__ b_pse,
                            const float* __restrict__ W_p1,
                            const float* __restrict__ b_p1,
                            const float* __restrict__ W_p2,
                            const float* __restrict__ W_m1,
                            const float* __restrict__ W_m2,
                            const float* __restrict__ W_ih,
                            const float* __restrict__ W_hh,
                            float* __restrict__ ccar,
                            float* __restrict__ din, float* __restrict__ lpos,
                            float* __restrict__ Wc, float* __restrict__ bc,
                            unsigned short* __restrict__ W2T,
                            unsigned short* __restrict__ W1T,
                            unsigned short* __restrict__ WmT,
                            unsigned short* __restrict__ Wgb,
                            unsigned short* __restrict__ Wp1b) {
  int stride = gridDim.x * blockDim.x;
  int idx0 = blockIdx.x * blockDim.x + threadIdx.x;
  for (int i = idx0; i < NB * HD; i += stride) ccar[i] = c0[i];
  for (int i = idx0; i < NB * 2; i += stride) lpos[i] = last_pos[i];
  for (int i = idx0; i < NB * ED; i += stride) {
    int r = i >> 6, e = i & 63;
    din[i] = b_se[e] + last_pos_rel[2 * r] * W_se[e]
                     + last_pos_rel[2 * r + 1] * W_se[ED + e];
  }
  for (int n = idx0; n < G4; n += stride) {
    float w0 = 0.f, w1 = 0.f, bb = b_p1[n];
    for (int e = 0; e < ED; ++e) {
      float wp = W_p1[e * G4 + n];
      w0 += W_pse[e] * wp;
      w1 += W_pse[ED + e] * wp;
      bb += b_pse[e] * wp;
    }
    Wc[n] = w0; Wc[G4 + n] = w1; bc[n] = bb;
  }
  // W2T: 1024 n x 512 k bf16
  for (int idx = idx0; idx < 1024 * 64; idx += stride) {
    int n = idx & 1023, k0 = (idx >> 10) << 3;
    unsigned pk0 = pack2bf(W_p2[(k0 + 0) * BNKD + n], W_p2[(k0 + 1) * BNKD + n]);
    unsigned pk1 = pack2bf(W_p2[(k0 + 2) * BNKD + n], W_p2[(k0 + 3) * BNKD + n]);
    unsigned pk2 = pack2bf(W_p2[(k0 + 4) * BNKD + n], W_p2[(k0 + 5) * BNKD + n]);
    unsigned pk3 = pack2bf(W_p2[(k0 + 6) * BNKD + n], W_p2[(k0 + 7) * BNKD + n]);
    *(uint4*)&W2T[n * G4 + k0] = make_uint4(pk0, pk1, pk2, pk3);
  }
  // W1T: 1024 n x 1152 k bf16
  for (int idx = idx0; idx < 1024 * 144; idx += stride) {
    int n = idx & 1023, k0 = (idx >> 10) << 3;
    unsigned pk0 = pack2bf(W_m1[(k0 + 0) * BNKD + n], W_m1[(k0 + 1) * BNKD + n]);
    unsigned pk1 = pack2bf(W_m1[(k0 + 2) * BNKD + n], W_m1[(k0 + 3) * BNKD + n]);
    unsigned pk2 = pack2bf(W_m1[(k0 + 4) * BNKD + n], W_m1[(k0 + 5) * BNKD + n]);
    unsigned pk3 = pack2bf(W_m1[(k0 + 6) * BNKD + n], W_m1[(k0 + 7) * BNKD + n]);
    *(uint4*)&W1T[n * KM1 + k0] = make_uint4(pk0, pk1, pk2, pk3);
  }
  // WmT: 128 n x 1024 k bf16
  for (int idx = idx0; idx < 128 * 128; idx += stride) {
    int n = idx & 127, k0 = (idx >> 7) << 3;
    unsigned pk0 = pack2bf(W_m2[(k0 + 0) * HD + n], W_m2[(k0 + 1) * HD + n]);
    unsigned pk1 = pack2bf(W_m2[(k0 + 2) * HD + n], W_m2[(k0 + 3) * HD + n]);
    unsigned pk2 = pack2bf(W_m2[(k0 + 4) * HD + n], W_m2[(k0 + 5) * HD + n]);
    unsigned pk3 = pack2bf(W_m2[(k0 + 6) * HD + n], W_m2[(k0 + 7) * HD + n]);
    *(uint4*)&WmT[n * BNKD + k0] = make_uint4(pk0, pk1, pk2, pk3);
  }
  // Wgb: [192][512] bf16, rows 0..63 = W_ih, 64..191 = W_hh
  for (int idx = idx0; idx < KG * G4; idx += stride) {
    int k = idx >> 9, n = idx & 511;
    float w = (k < ED) ? W_ih[k * G4 + n] : W_hh[(k - ED) * G4 + n];
    Wgb[idx] = f2bf(w);
  }
  // Wp1b: [128][512] bf16 from W_p1 rows 64..191
  for (int idx = idx0; idx < HD * G4; idx += stride) {
    int k = idx >> 9, n = idx & 511;
    Wp1b[idx] = f2bf(W_p1[(ED + k) * G4 + n]);
  }
}

// ---------------------------------------------------------------------------
// step A (AR=4, bf16 weights): LSTM cell + rel/curr pos + dec_in_next +
// Hp1 = h_new @ W_p1[64:] + bc + hacc_next init = b_m2. h -> mhA cols 0..127.
// ---------------------------------------------------------------------------
__global__ __launch_bounds__(256) void step_a(
    const float* __restrict__ hprev, const float* __restrict__ cprev,
    const float* __restrict__ din, const float* __restrict__ lpos_in,
    const unsigned short* __restrict__ Wgb,
    const float* __restrict__ b_ih, const float* __restrict__ b_hh,
    const float* __restrict__ W_hp, const float* __restrict__ b_hp,
    const float* __restrict__ W_se, const float* __restrict__ b_se,
    const unsigned short* __restrict__ Wp1b, const float* __restrict__ bc,
    const float* __restrict__ b_m2,
    unsigned short* __restrict__ mhA, float* __restrict__ cnext,
    float* __restrict__ dnext, float* __restrict__ lpos_out,
    float* __restrict__ Hp1, float* __restrict__ pred_out,
    float* __restrict__ hacc_next, int relu_in) {
  __shared__ float x[AR][192];   // [din(64) | h(128)]
  __shared__ float gg[AR][G4];
  __shared__ float hl[AR][HD];
  __shared__ float rp[AR][2];
  int t = threadIdx.x;
  int r0 = blockIdx.x * AR;

  for (int i = t; i < AR * ED; i += 256) { int r = i >> 6, k = i & 63; x[r][k] = din[(r0 + r) * ED + k]; }
  for (int i = t; i < AR * HD; i += 256) {
    int r = i >> 7, k = i & 127;
    float v = hprev[(r0 + r) * HD + k];
    if (relu_in) v = fmaxf(v, 0.f);
    x[r][ED + k] = v;
    hacc_next[(r0 + r) * HD + k] = b_m2[k];   // bias-init mlp2 accumulator
  }
  __syncthreads();

  float acc[AR][2];
#pragma unroll
  for (int r = 0; r < AR; ++r) { acc[r][0] = b_ih[t] + b_hh[t]; acc[r][1] = b_ih[t + 256] + b_hh[t + 256]; }
#pragma unroll 4
  for (int k = 0; k < KG; ++k) {
    float w0 = bf2f(Wgb[k * G4 + t]), w1 = bf2f(Wgb[k * G4 + t + 256]);
#pragma unroll
    for (int r = 0; r < AR; ++r) { float a = x[r][k]; acc[r][0] += a * w0; acc[r][1] += a * w1; }
  }
#pragma unroll
  for (int r = 0; r < AR; ++r) { gg[r][t] = acc[r][0]; gg[r][t + 256] = acc[r][1]; }
  __syncthreads();

  for (int i = t; i < AR * HD; i += 256) {
    int r = i >> 7, k = i & 127;
    float ig = gg[r][k], fg = gg[r][HD + k], gz = gg[r][2 * HD + k], og = gg[r][3 * HD + k];
    float si = 1.f / (1.f + expf(-ig));
    float sf = 1.f / (1.f + expf(-fg));
    float so = 1.f / (1.f + expf(-og));
    float gt = tanhf(gz);
    float c = sf * cprev[(r0 + r) * HD + k] + si * gt;
    float h = so * tanhf(c);
    cnext[(r0 + r) * HD + k] = c;
    mhA[(size_t)(r0 + r) * KM1 + k] = f2bf(h);
    hl[r][k] = h;
  }
  __syncthreads();

  if (t < AR * 2) {
    int r = t >> 1, d = t & 1;
    float s = b_hp[d];
    for (int k = 0; k < HD; ++k) s += hl[r][k] * W_hp[k * 2 + d];
    rp[r][d] = s;
    pred_out[(r0 + r) * 2 + d] = s;
    lpos_out[(r0 + r) * 2 + d] = s + lpos_in[(r0 + r) * 2 + d];
  }
  __syncthreads();

  for (int i = t; i < AR * ED; i += 256) {
    int r = i >> 6, e = i & 63;
    dnext[(r0 + r) * ED + e] = b_se[e] + rp[r][0] * W_se[e] + rp[r][1] * W_se[ED + e];
  }

  // Hp1 = h_new @ W_p1[64:192] + bc
  float bc0 = bc[t], bc1 = bc[t + 256];
  float acc2[AR][2];
#pragma unroll
  for (int r = 0; r < AR; ++r) { acc2[r][0] = bc0; acc2[r][1] = bc1; }
#pragma unroll 4
  for (int k = 0; k < HD; ++k) {
    float w0 = bf2f(Wp1b[k * G4 + t]), w1 = bf2f(Wp1b[k * G4 + t + 256]);
#pragma unroll
    for (int r = 0; r < AR; ++r) { float a = hl[r][k]; acc2[r][0] += a * w0; acc2[r][1] += a * w1; }
  }
#pragma unroll
  for (int r = 0; r < AR; ++r) {
    Hp1[(r0 + r) * G4 + t] = acc2[r][0];
    Hp1[(r0 + r) * G4 + t + 256] = acc2[r][1];
  }
}

// ---------------------------------------------------------------------------
// pool_fused v8: ygen folded in. Block = (scene, 128-col n-tile), grid 256
// (b = nt*32+s, scene->XCD s%8), 768 threads = 12 waves (3/SIMD).
// LDS: B 132KB + Hp1-scene bf16 25KB + Wc bf16 2KB (159KB). One barrier.
// Wave wv owns ipair wv: A-frags generated IN-REGISTER from LDS Hs/wc
// (x8 device redundancy only), B via conflict-free ds_read_b128.
// Zero barriers in k-loop; waves fully independent -> co-scheduling.
// ---------------------------------------------------------------------------
__global__ __launch_bounds__(768, 1) void pool_fused(
    const float* __restrict__ curr_pos, const float* __restrict__ Hp1,
    const float* __restrict__ Wc,
    const unsigned short* __restrict__ W2T, const float* __restrict__ b_p2,
    unsigned short* __restrict__ mhA) {
  __shared__ __align__(16) unsigned short Bl[128 * BPITCH];   // 132096 B
  __shared__ __align__(16) unsigned short Hs[24 * HPITCH];    // 24768 B
  __shared__ __align__(16) unsigned short wc0b[G4], wc1b[G4]; // 2048 B
  __shared__ float psx[NP], psy[NP];
  int t = threadIdx.x;
  int b = blockIdx.x;              // 256 = 8 ntiles * 32 scenes
  int s = b & 31, nt = b >> 5;     // scene -> XCD s%8
  int n0 = nt * 128;

  // stage B: 128 rows x 512 k (coalesced 16B)
  for (int idx = t; idx < 128 * 64; idx += 768) {
    int row = idx >> 6, ch = (idx & 63) << 3;
    *(uint4*)&Bl[row * BPITCH + ch] = *(const uint4*)&W2T[(size_t)(n0 + row) * G4 + ch];
  }
  // stage Hp1 scene slice (fp32 -> bf16)
  for (int idx = t; idx < 24 * 64; idx += 768) {
    int row = idx >> 6, ch = (idx & 63) << 3;
    const float* src = &Hp1[(size_t)(s * NP + row) * G4 + ch];
    float4 v0 = *(const float4*)src;
    float4 v1 = *(const float4*)(src + 4);
    uint4 pk;
    pk.x = pack2bf(v0.x, v0.y); pk.y = pack2bf(v0.z, v0.w);
    pk.z = pack2bf(v1.x, v1.y); pk.w = pack2bf(v1.z, v1.w);
    *(uint4*)&Hs[row * HPITCH + ch] = pk;
  }
  for (int i = t; i < G4; i += 768) {
    wc0b[i] = f2bf(Wc[i]);
    wc1b[i] = f2bf(Wc[G4 + i]);
  }
  if (t < NP) {
    psx[t] = curr_pos[(s * NP + t) * 2];
    psy[t] = curr_pos[(s * NP + t) * 2 + 1];
  }
  __syncthreads();

  int lane = t & 63, wv = t >> 6;  // wv = ipair 0..11
  int arow = lane & 15, ak = (lane >> 4) * 8, h = lane >> 4;
  int ip = wv;

  float rx[3], ry[3];
  int hoff[3];
#pragma unroll
  for (int f = 0; f < 3; ++f) {
    int m = f * 16 + arow;
    int j = m % 24, g = m / 24;
    rx[f] = psx[j] - psx[ip * 2 + g];
    ry[f] = psy[j] - psy[ip * 2 + g];
    hoff[f] = j * HPITCH + ak;
  }
  int boff[8];
#pragma unroll
  for (int nf = 0; nf < 8; ++nf) boff[nf] = (nf * 16 + arow) * BPITCH + ak;

  f32x4 acc[3][8];
#pragma unroll
  for (int f = 0; f < 3; ++f)
#pragma unroll
    for (int nf = 0; nf < 8; ++nf) acc[f][nf] = (f32x4){0.f, 0.f, 0.f, 0.f};

  for (int kt = 0; kt < 16; ++kt) {
    int k0 = kt * 32;
    u16x8 w0v = *(const u16x8*)&wc0b[k0 + ak];
    u16x8 w1v = *(const u16x8*)&wc1b[k0 + ak];
    bf16x8 af[3];
#pragma unroll
    for (int f = 0; f < 3; ++f) {
      u16x8 hp = *(const u16x8*)&Hs[hoff[f] + k0];
      float rxf = rx[f], ryf = ry[f];
#pragma unroll
      for (int q = 0; q < 8; ++q) {
        float v = bf2f(hp[q]) + rxf * bf2f(w0v[q]) + ryf * bf2f(w1v[q]);
        af[f][q] = (__bf16)fmaxf(v, 0.f);
      }
    }
#pragma unroll
    for (int nf = 0; nf < 8; ++nf) {
      bf16x8 bfr = *(const bf16x8*)&Bl[boff[nf] + k0];
      acc[0][nf] = __builtin_amdgcn_mfma_f32_16x16x32_bf16(af[0], bfr, acc[0][nf], 0, 0, 0);
      acc[1][nf] = __builtin_amdgcn_mfma_f32_16x16x32_bf16(af[1], bfr, acc[1][nf], 0, 0, 0);
      acc[2][nf] = __builtin_amdgcn_mfma_f32_16x16x32_bf16(af[2], bfr, acc[2][nf], 0, 0, 0);
    }
  }

  // epilogue: max over j per ped group. frag rows: f0=g0 j0-15,
  // f1 lo=g0 j16-23 / hi=g1 j0-7, f2=g1 j8-23. C: row=(lane>>4)*4+reg.
  int iA = s * NP + ip * 2;
#pragma unroll
  for (int nf = 0; nf < 8; ++nf) {
    f32x4 a0 = acc[0][nf], a1 = acc[1][nf], a2 = acc[2][nf];
    float v0 = fmaxf(fmaxf(a0[0], a0[1]), fmaxf(a0[2], a0[3]));
    float v1 = fmaxf(fmaxf(a1[0], a1[1]), fmaxf(a1[2], a1[3]));
    float v2 = fmaxf(fmaxf(a2[0], a2[1]), fmaxf(a2[2], a2[3]));
    v0 = fmaxf(v0, __shfl_xor(v0, 16));
    v1 = fmaxf(v1, __shfl_xor(v1, 16));
    v2 = fmaxf(v2, __shfl_xor(v2, 16));
    float xx = (h < 2) ? fmaxf(v0, v1) : v0;    // g0 = f0 all + f1 lo
    xx = fmaxf(xx, __shfl_xor(xx, 32));
    float yy = (h >= 2) ? fmaxf(v2, v1) : v2;   // g1 = f1 hi + f2 all
    yy = fmaxf(yy, __shfl_xor(yy, 32));
    int col = n0 + nf * 16 + (lane & 15);
    float bb = b_p2[col];
    xx = fmaxf(xx + bb, 0.f);
    yy = fmaxf(yy + bb, 0.f);
    if (h == 0) mhA[(size_t)iA * KM1 + HD + col] = f2bf(xx);
    if (h == 1) mhA[((size_t)iA + 1) * KM1 + HD + col] = f2bf(yy);
  }
}

// ---------------------------------------------------------------------------
// mlp1_fused: stage1 mh_tile = relu(mhA @ W_m1 + b_m1) (32x128, regs),
// stage2 hacc += mh_tile @ W_m2[n0:n0+128,:] via bf16 hi+lo MFMA + atomicAdd.
// ---------------------------------------------------------------------------
__global__ __launch_bounds__(256) void mlp1_fused(
    const unsigned short* __restrict__ mhA,
    const unsigned short* __restrict__ W1T, const float* __restrict__ b_m1,
    const unsigned short* __restrict__ WmT, float* __restrict__ hacc) {
  __shared__ __align__(16) float Pl[32][132];
  int t = threadIdx.x, b = blockIdx.x;   // 192 = 24 mt * 8 nt
  int mt = b >> 3, nt = b & 7;
  int r0 = mt * 32, n0 = nt * 128;
  int lane = t & 63, wid = t >> 6, wm = wid >> 1, wn = wid & 1;
  int arow = lane & 15, ak = (lane >> 4) * 8;
  int h = lane >> 4;

  f32x4 acc0[4];
#pragma unroll
  for (int nf = 0; nf < 4; ++nf) acc0[nf] = (f32x4){0.f, 0.f, 0.f, 0.f};
  int mrow = r0 + wm * 16 + arow;
  const unsigned short* bp[4];
#pragma unroll
  for (int nf = 0; nf < 4; ++nf)
    bp[nf] = W1T + (size_t)(n0 + wn * 64 + nf * 16 + arow) * KM1 + ak;
  const unsigned short* arow_m = mhA + (size_t)mrow * KM1 + ak;

#pragma unroll 4
  for (int kt = 0; kt < 36; ++kt) {
    bf16x8 a = *(const bf16x8*)(arow_m + kt * 32);
#pragma unroll
    for (int nf = 0; nf < 4; ++nf) {
      bf16x8 bb = *(const bf16x8*)(bp[nf] + kt * 32);
      acc0[nf] = __builtin_amdgcn_mfma_f32_16x16x32_bf16(a, bb, acc0[nf], 0, 0, 0);
    }
  }

  // P = relu(acc0 + b_m1) -> LDS (fp32)
#pragma unroll
  for (int nf = 0; nf < 4; ++nf) {
    int colp = wn * 64 + nf * 16 + arow;
    float bb = b_m1[n0 + colp];
#pragma unroll
    for (int rr = 0; rr < 4; ++rr)
      Pl[wm * 16 + h * 4 + rr][colp] = fmaxf(acc0[nf][rr] + bb, 0.f);
  }
  __syncthreads();

  // stage 2: (32x128 P-tile) @ WmT[:, n0:n0+128]^T -> 32x128 partial of h
  f32x4 acc2[4];
#pragma unroll
  for (int nf = 0; nf < 4; ++nf) acc2[nf] = (f32x4){0.f, 0.f, 0.f, 0.f};
  const unsigned short* b2p[4];
#pragma unroll
  for (int nf = 0; nf < 4; ++nf)
    b2p[nf] = WmT + (size_t)(wn * 64 + nf * 16 + arow) * BNKD + n0 + ak;
  const float* prow = &Pl[wm * 16 + arow][0];

#pragma unroll
  for (int k2 = 0; k2 < 4; ++k2) {
    u16x8 uh, ul;
#pragma unroll
    for (int q = 0; q < 8; ++q) {
      float vv = prow[k2 * 32 + ak + q];
      unsigned short hh = f2bf(vv);
      uh[q] = hh;
      ul[q] = f2bf(vv - bf2f(hh));
    }
    bf16x8 ahi = __builtin_bit_cast(bf16x8, uh);
    bf16x8 alo = __builtin_bit_cast(bf16x8, ul);
#pragma unroll
    for (int nf = 0; nf < 4; ++nf) {
      bf16x8 bb = *(const bf16x8*)(b2p[nf] + k2 * 32);
      acc2[nf] = __builtin_amdgcn_mfma_f32_16x16x32_bf16(ahi, bb, acc2[nf], 0, 0, 0);
      acc2[nf] = __builtin_amdgcn_mfma_f32_16x16x32_bf16(alo, bb, acc2[nf], 0, 0, 0);
    }
  }
#pragma unroll
  for (int nf = 0; nf < 4; ++nf)
#pragma unroll
    for (int rr = 0; rr < 4; ++rr)
      atomicAdd(&hacc[(size_t)(r0 + wm * 16 + h * 4 + rr) * HD + wn * 64 + nf * 16 + arow],
                acc2[nf][rr]);
}

// ---------------------------------------------------------------------------
// final: h_fin = relu(hacc)
// ---------------------------------------------------------------------------
__global__ void final_h(const float* __restrict__ hacc, float* __restrict__ out) {
  int i = blockIdx.x * 256 + threadIdx.x;
  if (i < NB * HD) out[i] = fmaxf(hacc[i], 0.f);
}

// ---------------------------------------------------------------------------
extern "C" void kernel_launch(void* const* d_in, const int* in_sizes, int n_in,
                              void* d_out, int out_size, void* d_ws, size_t ws_size,
                              hipStream_t stream) {
  const float* last_pos     = (const float*)d_in[0];
  const float* last_pos_rel = (const float*)d_in[1];
  const float* h0   = (const float*)d_in[2];
  const float* c0   = (const float*)d_in[3];
  const float* W_se = (const float*)d_in[5];
  const float* b_se = (const float*)d_in[6];
  const float* W_ih = (const float*)d_in[7];
  const float* b_ih = (const float*)d_in[8];
  const float* W_hh = (const float*)d_in[9];
  const float* b_hh = (const float*)d_in[10];
  const float* W_hp = (const float*)d_in[11];
  const float* b_hp = (const float*)d_in[12];
  const float* W_pse = (const float*)d_in[13];
  const float* b_pse = (const float*)d_in[14];
  const float* W_p1 = (const float*)d_in[15];
  const float* b_p1 = (const float*)d_in[16];
  const float* W_p2 = (const float*)d_in[17];
  const float* b_p2 = (const float*)d_in[18];
  const float* W_m1 = (const float*)d_in[19];
  const float* b_m1 = (const float*)d_in[20];
  const float* W_m2 = (const float*)d_in[21];
  const float* b_m2 = (const float*)d_in[22];

  float* ws = (float*)d_ws;
  float* hacc[2]  = { ws,           ws + 98304 };
  float* ccar[2]  = { ws + 196608,  ws + 294912 };
  float* din[2]   = { ws + 393216,  ws + 442368 };
  float* lposb[2] = { ws + 491520,  ws + 493056 };
  float* Hp1  = ws + 494592;                                // 393216 floats
  float* Wc   = ws + 887808;                                // 1024
  float* bc   = ws + 888832;                                // 512
  unsigned short* W2T  = (unsigned short*)(ws + 889344);    // 1024x512 bf16
  unsigned short* W1T  = (unsigned short*)(ws + 1151488);   // 1024x1152 bf16
  unsigned short* WmT  = (unsigned short*)(ws + 1741312);   // 128x1024 bf16
  unsigned short* mhA  = (unsigned short*)(ws + 1806848);   // 768x1152 bf16
  unsigned short* Wgb  = (unsigned short*)(ws + 2249216);   // 192x512 bf16
  unsigned short* Wp1b = (unsigned short*)(ws + 2298368);   // 128x512 bf16

  float* pred = (float*)d_out;

  init_kernel<<<128, 256, 0, stream>>>(last_pos, last_pos_rel, c0,
                                       W_se, b_se, W_pse, b_pse, W_p1, b_p1,
                                       W_p2, W_m1, W_m2, W_ih, W_hh,
                                       ccar[0], din[0], lposb[0],
                                       Wc, bc, W2T, W1T, WmT, Wgb, Wp1b);

  for (int t = 0; t < TSTEPS; ++t) {
    int a = t & 1, b = (t + 1) & 1;
    step_a<<<NB / AR, 256, 0, stream>>>(
        t == 0 ? h0 : hacc[a], ccar[a], din[a], lposb[a],
        Wgb, b_ih, b_hh, W_hp, b_hp, W_se, b_se, Wp1b, bc, b_m2,
        mhA, ccar[b], din[b], lposb[b], Hp1, pred + t * NB * 2,
        hacc[b], t == 0 ? 0 : 1);
    pool_fused<<<NS * 8, 768, 0, stream>>>(lposb[b], Hp1, Wc, W2T, b_p2, mhA);
    mlp1_fused<<<192, 256, 0, stream>>>(mhA, W1T, b_m1, WmT, hacc[b]);
  }

  final_h<<<384, 256, 0, stream>>>(hacc[0], (float*)d_out + TSTEPS * NB * 2);
}

// Round 11
// 1130.592 us; speedup vs baseline: 1.3659x; 1.0322x over previous
//
#include <hip/hip_runtime.h>
#include <math.h>

// Problem constants (uniform scenes per reference)
#define NB 768      // batch = S*P
#define NS 32       // scenes
#define NP 24       // peds/scene
#define ED 64       // embedding dim E
#define HD 128      // hidden H
#define G4 512      // 4*H
#define BNKD 1024   // bottleneck
#define KM1 1152    // H + BNK
#define KG 192      // E + H
#define TSTEPS 12
#define BPITCH 516  // pool B LDS row pitch in shorts (1032B -> conflict-free)
#define HPITCH 516

typedef __bf16 bf16x8 __attribute__((ext_vector_type(8)));
typedef float f32x4 __attribute__((ext_vector_type(4)));
typedef unsigned short u16x8 __attribute__((ext_vector_type(8)));

__device__ __forceinline__ unsigned short f2bf(float f) {
  unsigned u = __float_as_uint(f);
  u = (u + 0x7FFFu + ((u >> 16) & 1u)) >> 16;   // RNE
  return (unsigned short)u;
}
__device__ __forceinline__ unsigned pack2bf(float a, float b) {
  return (unsigned)f2bf(a) | ((unsigned)f2bf(b) << 16);
}
__device__ __forceinline__ float bf2f(unsigned short h) {
  return __uint_as_float(((unsigned)h) << 16);
}

// ---------------------------------------------------------------------------
// init: carries, dec_in0, folded pool-L1 weights (Wc, bc), bf16 prepacks:
// W2T[n][k]=W_p2[k][n]; W1T[n][k]=W_m1[k][n]; WmT[n][k]=W_m2[k][n];
// Wgbn[col][k] = [W_ih;W_hh]^T bf16 (n-major); Wp1T2[n][k] = W_p1[64:]^T bf16.
// ---------------------------------------------------------------------------
__global__ void init_kernel(const float* __restrict__ last_pos,
                            const float* __restrict__ last_pos_rel,
                            const float* __restrict__ c0,
                            const float* __restrict__ W_se,
                            const float* __restrict__ b_se,
                            const float* __restrict__ W_pse,
                            const float* __restrict__ b_pse,
                            const float* __restrict__ W_p1,
                            const float* __restrict__ b_p1,
                            const float* __restrict__ W_p2,
                            const float* __restrict__ W_m1,
                            const float* __restrict__ W_m2,
                            const float* __restrict__ W_ih,
                            const float* __restrict__ W_hh,
                            float* __restrict__ ccar,
                            float* __restrict__ din, float* __restrict__ lpos,
                            float* __restrict__ Wc, float* __restrict__ bc,
                            unsigned short* __restrict__ W2T,
                            unsigned short* __restrict__ W1T,
                            unsigned short* __restrict__ WmT,
                            unsigned short* __restrict__ Wgbn,
                            unsigned short* __restrict__ Wp1T2) {
  int stride = gridDim.x * blockDim.x;
  int idx0 = blockIdx.x * blockDim.x + threadIdx.x;
  for (int i = idx0; i < NB * HD; i += stride) ccar[i] = c0[i];
  for (int i = idx0; i < NB * 2; i += stride) lpos[i] = last_pos[i];
  for (int i = idx0; i < NB * ED; i += stride) {
    int r = i >> 6, e = i & 63;
    din[i] = b_se[e] + last_pos_rel[2 * r] * W_se[e]
                     + last_pos_rel[2 * r + 1] * W_se[ED + e];
  }
  for (int n = idx0; n < G4; n += stride) {
    float w0 = 0.f, w1 = 0.f, bb = b_p1[n];
    for (int e = 0; e < ED; ++e) {
      float wp = W_p1[e * G4 + n];
      w0 += W_pse[e] * wp;
      w1 += W_pse[ED + e] * wp;
      bb += b_pse[e] * wp;
    }
    Wc[n] = w0; Wc[G4 + n] = w1; bc[n] = bb;
  }
  // W2T: 1024 n x 512 k bf16
  for (int idx = idx0; idx < 1024 * 64; idx += stride) {
    int n = idx & 1023, k0 = (idx >> 10) << 3;
    unsigned pk0 = pack2bf(W_p2[(k0 + 0) * BNKD + n], W_p2[(k0 + 1) * BNKD + n]);
    unsigned pk1 = pack2bf(W_p2[(k0 + 2) * BNKD + n], W_p2[(k0 + 3) * BNKD + n]);
    unsigned pk2 = pack2bf(W_p2[(k0 + 4) * BNKD + n], W_p2[(k0 + 5) * BNKD + n]);
    unsigned pk3 = pack2bf(W_p2[(k0 + 6) * BNKD + n], W_p2[(k0 + 7) * BNKD + n]);
    *(uint4*)&W2T[n * G4 + k0] = make_uint4(pk0, pk1, pk2, pk3);
  }
  // W1T: 1024 n x 1152 k bf16
  for (int idx = idx0; idx < 1024 * 144; idx += stride) {
    int n = idx & 1023, k0 = (idx >> 10) << 3;
    unsigned pk0 = pack2bf(W_m1[(k0 + 0) * BNKD + n], W_m1[(k0 + 1) * BNKD + n]);
    unsigned pk1 = pack2bf(W_m1[(k0 + 2) * BNKD + n], W_m1[(k0 + 3) * BNKD + n]);
    unsigned pk2 = pack2bf(W_m1[(k0 + 4) * BNKD + n], W_m1[(k0 + 5) * BNKD + n]);
    unsigned pk3 = pack2bf(W_m1[(k0 + 6) * BNKD + n], W_m1[(k0 + 7) * BNKD + n]);
    *(uint4*)&W1T[n * KM1 + k0] = make_uint4(pk0, pk1, pk2, pk3);
  }
  // WmT: 128 n x 1024 k bf16
  for (int idx = idx0; idx < 128 * 128; idx += stride) {
    int n = idx & 127, k0 = (idx >> 7) << 3;
    unsigned pk0 = pack2bf(W_m2[(k0 + 0) * HD + n], W_m2[(k0 + 1) * HD + n]);
    unsigned pk1 = pack2bf(W_m2[(k0 + 2) * HD + n], W_m2[(k0 + 3) * HD + n]);
    unsigned pk2 = pack2bf(W_m2[(k0 + 4) * HD + n], W_m2[(k0 + 5) * HD + n]);
    unsigned pk3 = pack2bf(W_m2[(k0 + 6) * HD + n], W_m2[(k0 + 7) * HD + n]);
    *(uint4*)&WmT[n * BNKD + k0] = make_uint4(pk0, pk1, pk2, pk3);
  }
  // Wgbn: [512 col][192 k] bf16; k<64 from W_ih, else W_hh
  for (int idx = idx0; idx < 512 * 24; idx += stride) {
    int col = idx / 24, kc = (idx % 24) * 8;
    unsigned short v[8];
#pragma unroll
    for (int q = 0; q < 8; ++q) {
      int k = kc + q;
      float w = (k < ED) ? W_ih[k * G4 + col] : W_hh[(k - ED) * G4 + col];
      v[q] = f2bf(w);
    }
    uint4 pk;
    pk.x = v[0] | (v[1] << 16); pk.y = v[2] | (v[3] << 16);
    pk.z = v[4] | (v[5] << 16); pk.w = v[6] | (v[7] << 16);
    *(uint4*)&Wgbn[(size_t)col * KG + kc] = pk;
  }
  // Wp1T2: [512 n][128 k] bf16 from W_p1 rows 64..191
  for (int idx = idx0; idx < 512 * 16; idx += stride) {
    int n = idx >> 4, kc = (idx & 15) << 3;
    unsigned short v[8];
#pragma unroll
    for (int q = 0; q < 8; ++q) v[q] = f2bf(W_p1[(ED + kc + q) * G4 + n]);
    uint4 pk;
    pk.x = v[0] | (v[1] << 16); pk.y = v[2] | (v[3] << 16);
    pk.z = v[4] | (v[5] << 16); pk.w = v[6] | (v[7] << 16);
    *(uint4*)&Wp1T2[(size_t)n * HD + kc] = pk;
  }
}

// ---------------------------------------------------------------------------
// step_a v10: pure LSTM cell, gate-aligned hid-split. Block = (rowgroup of 4,
// hid-half): computes all 4 gates for its 64 hidden idxs -> cell update is
// block-local. Grid 384 (1.5 blocks/CU). Writes cnext + h (bf16 -> mhA cols
// 0..127) + hacc_next bias-init.
// ---------------------------------------------------------------------------
__global__ __launch_bounds__(256) void step_a(
    const float* __restrict__ hprev, const float* __restrict__ cprev,
    const float* __restrict__ din,
    const unsigned short* __restrict__ Wgbn,
    const float* __restrict__ b_ih, const float* __restrict__ b_hh,
    const float* __restrict__ b_m2,
    unsigned short* __restrict__ mhA, float* __restrict__ cnext,
    float* __restrict__ hacc_next, int relu_in) {
  __shared__ __align__(16) float x[4][200];   // [din(64) | h(128)], padded
  __shared__ float gg[4][4][64];              // [row][gate][hid-c]
  int t = threadIdx.x, b = blockIdx.x;
  int rg = b >> 1, hh = b & 1, r0 = rg * 4;

  { int r = t >> 6, k = t & 63; x[r][k] = din[(r0 + r) * ED + k]; }
  for (int i = t; i < 4 * HD; i += 256) {
    int r = i >> 7, k = i & 127;
    float v = hprev[(r0 + r) * HD + k];
    if (relu_in) v = fmaxf(v, 0.f);
    x[r][ED + k] = v;
    hacc_next[(r0 + r) * HD + k] = b_m2[k];   // redundant x2 blocks, same value
  }
  __syncthreads();

  int gq = t >> 6, c = t & 63;
  int col = gq * 128 + hh * 64 + c;
  float bb = b_ih[col] + b_hh[col];
  float a0 = bb, a1 = bb, a2 = bb, a3 = bb;
  const unsigned short* wp = Wgbn + (size_t)col * KG;
#pragma unroll 2
  for (int kc = 0; kc < KG; kc += 8) {
    u16x8 wv = *(const u16x8*)(wp + kc);
    float4 x0a = *(const float4*)&x[0][kc], x0b = *(const float4*)&x[0][kc + 4];
    float4 x1a = *(const float4*)&x[1][kc], x1b = *(const float4*)&x[1][kc + 4];
    float4 x2a = *(const float4*)&x[2][kc], x2b = *(const float4*)&x[2][kc + 4];
    float4 x3a = *(const float4*)&x[3][kc], x3b = *(const float4*)&x[3][kc + 4];
    float w0 = bf2f(wv[0]), w1 = bf2f(wv[1]), w2 = bf2f(wv[2]), w3 = bf2f(wv[3]);
    float w4 = bf2f(wv[4]), w5 = bf2f(wv[5]), w6 = bf2f(wv[6]), w7 = bf2f(wv[7]);
    a0 += x0a.x * w0 + x0a.y * w1 + x0a.z * w2 + x0a.w * w3
        + x0b.x * w4 + x0b.y * w5 + x0b.z * w6 + x0b.w * w7;
    a1 += x1a.x * w0 + x1a.y * w1 + x1a.z * w2 + x1a.w * w3
        + x1b.x * w4 + x1b.y * w5 + x1b.z * w6 + x1b.w * w7;
    a2 += x2a.x * w0 + x2a.y * w1 + x2a.z * w2 + x2a.w * w3
        + x2b.x * w4 + x2b.y * w5 + x2b.z * w6 + x2b.w * w7;
    a3 += x3a.x * w0 + x3a.y * w1 + x3a.z * w2 + x3a.w * w3
        + x3b.x * w4 + x3b.y * w5 + x3b.z * w6 + x3b.w * w7;
  }
  gg[0][gq][c] = a0; gg[1][gq][c] = a1; gg[2][gq][c] = a2; gg[3][gq][c] = a3;
  __syncthreads();

  // cell update (gate order i,f,g,o), 256 threads = 4 rows x 64 hid
  {
    int r2 = t >> 6, c2 = t & 63, hid = hh * 64 + c2;
    float ig = gg[r2][0][c2], fg = gg[r2][1][c2];
    float gz = gg[r2][2][c2], og = gg[r2][3][c2];
    float si = 1.f / (1.f + expf(-ig));
    float sf = 1.f / (1.f + expf(-fg));
    float so = 1.f / (1.f + expf(-og));
    float gt = tanhf(gz);
    float cn = sf * cprev[(r0 + r2) * HD + hid] + si * gt;
    float hv = so * tanhf(cn);
    cnext[(r0 + r2) * HD + hid] = cn;
    mhA[(size_t)(r0 + r2) * KM1 + hid] = f2bf(hv);
  }
}

// ---------------------------------------------------------------------------
// pool_fused v10: prologue computes rel_pos/curr_pos (dots from mhA h),
// Hp1 via MFMA (A direct from row-major mhA h!) -> Hs LDS (+bc), and nt0
// writes dnext/lpos/pred. Then v8 main loop (Y-gen in-reg, B LDS-resident,
// zero k-loop barriers). Block = (scene, 128-col n-tile), 768 thr (12 waves).
// ---------------------------------------------------------------------------
__global__ __launch_bounds__(768, 1) void pool_fused(
    const float* __restrict__ lpos_in,
    const float* __restrict__ Wc, const float* __restrict__ bc,
    const unsigned short* __restrict__ W2T,
    const unsigned short* __restrict__ Wp1T2,
    const float* __restrict__ b_p2,
    const float* __restrict__ W_hp, const float* __restrict__ b_hp,
    const float* __restrict__ W_se, const float* __restrict__ b_se,
    float* __restrict__ lpos_out, float* __restrict__ dnext,
    float* __restrict__ pred_out,
    unsigned short* __restrict__ mhA) {
  __shared__ __align__(16) unsigned short Bl[128 * BPITCH];   // 132096 B
  __shared__ __align__(16) unsigned short Hs[24 * HPITCH];    // 24768 B
  __shared__ __align__(16) unsigned short wc0b[G4], wc1b[G4]; // 2048 B
  __shared__ float psx[NP], psy[NP], rpx[NP], rpy[NP];
  int t = threadIdx.x, b = blockIdx.x;    // 256 = 8 ntiles * 32 scenes
  int s = b & 31, nt = b >> 5;            // scene -> XCD s%8
  int n0 = nt * 128;

  // stage B
  for (int idx = t; idx < 128 * 64; idx += 768) {
    int row = idx >> 6, ch = (idx & 63) << 3;
    *(uint4*)&Bl[row * BPITCH + ch] = *(const uint4*)&W2T[(size_t)(n0 + row) * G4 + ch];
  }
  for (int i = t; i < G4; i += 768) { wc0b[i] = f2bf(Wc[i]); wc1b[i] = f2bf(Wc[G4 + i]); }

  // rel_pos dots: 768 thr = 24 rows x 2 d x 16 k-chunks
  {
    int row = t >> 5, d = (t >> 4) & 1, kc = t & 15;
    const unsigned short* hr = mhA + (size_t)(s * NP + row) * KM1 + kc * 8;
    float p = 0.f;
#pragma unroll
    for (int q = 0; q < 8; ++q) p += bf2f(hr[q]) * W_hp[(kc * 8 + q) * 2 + d];
    p += __shfl_xor(p, 1); p += __shfl_xor(p, 2);
    p += __shfl_xor(p, 4); p += __shfl_xor(p, 8);
    if (kc == 0) {
      float rel = p + b_hp[d];
      float cur = rel + lpos_in[(s * NP + row) * 2 + d];
      if (d == 0) { rpx[row] = rel; psx[row] = cur; }
      else        { rpy[row] = rel; psy[row] = cur; }
    }
  }

  int lane = t & 63, wv = t >> 6;
  int arow = lane & 15, ak = (lane >> 4) * 8, h = lane >> 4;

  // Hp1 MFMA -> Hs (+bc). 16 tasks = 2 Mfrag x 8 colgroups.
  for (int pass = 0; pass < 2; ++pass) {
    if (pass == 1 && wv >= 4) break;
    int task = (pass == 0) ? wv : 12 + wv;
    int mf = task >> 3, cg = task & 7;
    int m = mf * 16 + arow; if (m > 23) m = 23;
    const unsigned short* ap = mhA + (size_t)(s * NP + m) * KM1 + ak;
    f32x4 hacc4[4];
#pragma unroll
    for (int nf = 0; nf < 4; ++nf) hacc4[nf] = (f32x4){0.f, 0.f, 0.f, 0.f};
#pragma unroll
    for (int kt = 0; kt < 4; ++kt) {
      bf16x8 a = *(const bf16x8*)(ap + kt * 32);
#pragma unroll
      for (int nf = 0; nf < 4; ++nf) {
        bf16x8 bb = *(const bf16x8*)(Wp1T2 + (size_t)(cg * 64 + nf * 16 + arow) * HD + kt * 32 + ak);
        hacc4[nf] = __builtin_amdgcn_mfma_f32_16x16x32_bf16(a, bb, hacc4[nf], 0, 0, 0);
      }
    }
#pragma unroll
    for (int nf = 0; nf < 4; ++nf) {
      int col = cg * 64 + nf * 16 + arow;
      float bcv = bc[col];
#pragma unroll
      for (int rr = 0; rr < 4; ++rr) {
        int row = mf * 16 + h * 4 + rr;
        if (row < 24) Hs[row * HPITCH + col] = f2bf(hacc4[nf][rr] + bcv);
      }
    }
  }
  __syncthreads();

  // nt0 extras: pred / lpos_out / dec_in_next
  if (nt == 0) {
    if (t < 48) {
      int row = t >> 1, d = t & 1;
      pred_out[(s * NP + row) * 2 + d] = d ? rpy[row] : rpx[row];
      lpos_out[(s * NP + row) * 2 + d] = d ? psy[row] : psx[row];
    }
    for (int idx = t; idx < NP * ED; idx += 768) {
      int row = idx >> 6, e = idx & 63;
      dnext[(s * NP + row) * ED + e] = b_se[e] + rpx[row] * W_se[e] + rpy[row] * W_se[ED + e];
    }
  }

  // main loop (v8): wave wv = ipair; Y-gen in-reg from Hs/wc; B from Bl
  int ip = wv;
  float rx[3], ry[3];
  int hoff[3];
#pragma unroll
  for (int f = 0; f < 3; ++f) {
    int m = f * 16 + arow;
    int j = m % 24, g = m / 24;
    rx[f] = psx[j] - psx[ip * 2 + g];
    ry[f] = psy[j] - psy[ip * 2 + g];
    hoff[f] = j * HPITCH + ak;
  }
  int boff[8];
#pragma unroll
  for (int nf = 0; nf < 8; ++nf) boff[nf] = (nf * 16 + arow) * BPITCH + ak;

  f32x4 acc[3][8];
#pragma unroll
  for (int f = 0; f < 3; ++f)
#pragma unroll
    for (int nf = 0; nf < 8; ++nf) acc[f][nf] = (f32x4){0.f, 0.f, 0.f, 0.f};

  for (int kt = 0; kt < 16; ++kt) {
    int k0 = kt * 32;
    u16x8 w0v = *(const u16x8*)&wc0b[k0 + ak];
    u16x8 w1v = *(const u16x8*)&wc1b[k0 + ak];
    bf16x8 af[3];
#pragma unroll
    for (int f = 0; f < 3; ++f) {
      u16x8 hp = *(const u16x8*)&Hs[hoff[f] + k0];
      float rxf = rx[f], ryf = ry[f];
#pragma unroll
      for (int q = 0; q < 8; ++q) {
        float v = bf2f(hp[q]) + rxf * bf2f(w0v[q]) + ryf * bf2f(w1v[q]);
        af[f][q] = (__bf16)fmaxf(v, 0.f);
      }
    }
#pragma unroll
    for (int nf = 0; nf < 8; ++nf) {
      bf16x8 bfr = *(const bf16x8*)&Bl[boff[nf] + k0];
      acc[0][nf] = __builtin_amdgcn_mfma_f32_16x16x32_bf16(af[0], bfr, acc[0][nf], 0, 0, 0);
      acc[1][nf] = __builtin_amdgcn_mfma_f32_16x16x32_bf16(af[1], bfr, acc[1][nf], 0, 0, 0);
      acc[2][nf] = __builtin_amdgcn_mfma_f32_16x16x32_bf16(af[2], bfr, acc[2][nf], 0, 0, 0);
    }
  }

  // epilogue: max over j per ped group. frag rows: f0=g0 j0-15,
  // f1 lo=g0 j16-23 / hi=g1 j0-7, f2=g1 j8-23. C: row=(lane>>4)*4+reg.
  int iA = s * NP + ip * 2;
#pragma unroll
  for (int nf = 0; nf < 8; ++nf) {
    f32x4 a0 = acc[0][nf], a1 = acc[1][nf], a2 = acc[2][nf];
    float v0 = fmaxf(fmaxf(a0[0], a0[1]), fmaxf(a0[2], a0[3]));
    float v1 = fmaxf(fmaxf(a1[0], a1[1]), fmaxf(a1[2], a1[3]));
    float v2 = fmaxf(fmaxf(a2[0], a2[1]), fmaxf(a2[2], a2[3]));
    v0 = fmaxf(v0, __shfl_xor(v0, 16));
    v1 = fmaxf(v1, __shfl_xor(v1, 16));
    v2 = fmaxf(v2, __shfl_xor(v2, 16));
    float xx = (h < 2) ? fmaxf(v0, v1) : v0;    // g0 = f0 all + f1 lo
    xx = fmaxf(xx, __shfl_xor(xx, 32));
    float yy = (h >= 2) ? fmaxf(v2, v1) : v2;   // g1 = f1 hi + f2 all
    yy = fmaxf(yy, __shfl_xor(yy, 32));
    int col = n0 + nf * 16 + (lane & 15);
    float bb2 = b_p2[col];
    xx = fmaxf(xx + bb2, 0.f);
    yy = fmaxf(yy + bb2, 0.f);
    if (h == 0) mhA[(size_t)iA * KM1 + HD + col] = f2bf(xx);
    if (h == 1) mhA[((size_t)iA + 1) * KM1 + HD + col] = f2bf(yy);
  }
}

// ---------------------------------------------------------------------------
// mlp1_fused: stage1 mh_tile = relu(mhA @ W_m1 + b_m1) (32x128, regs),
// stage2 hacc += mh_tile @ W_m2[n0:n0+128,:] via bf16 hi+lo MFMA + atomicAdd.
// ---------------------------------------------------------------------------
__global__ __launch_bounds__(256) void mlp1_fused(
    const unsigned short* __restrict__ mhA,
    const unsigned short* __restrict__ W1T, const float* __restrict__ b_m1,
    const unsigned short* __restrict__ WmT, float* __restrict__ hacc) {
  __shared__ __align__(16) float Pl[32][132];
  int t = threadIdx.x, b = blockIdx.x;   // 192 = 24 mt * 8 nt
  int mt = b >> 3, nt = b & 7;
  int r0 = mt * 32, n0 = nt * 128;
  int lane = t & 63, wid = t >> 6, wm = wid >> 1, wn = wid & 1;
  int arow = lane & 15, ak = (lane >> 4) * 8;
  int h = lane >> 4;

  f32x4 acc0[4];
#pragma unroll
  for (int nf = 0; nf < 4; ++nf) acc0[nf] = (f32x4){0.f, 0.f, 0.f, 0.f};
  int mrow = r0 + wm * 16 + arow;
  const unsigned short* bp[4];
#pragma unroll
  for (int nf = 0; nf < 4; ++nf)
    bp[nf] = W1T + (size_t)(n0 + wn * 64 + nf * 16 + arow) * KM1 + ak;
  const unsigned short* arow_m = mhA + (size_t)mrow * KM1 + ak;

#pragma unroll 4
  for (int kt = 0; kt < 36; ++kt) {
    bf16x8 a = *(const bf16x8*)(arow_m + kt * 32);
#pragma unroll
    for (int nf = 0; nf < 4; ++nf) {
      bf16x8 bb = *(const bf16x8*)(bp[nf] + kt * 32);
      acc0[nf] = __builtin_amdgcn_mfma_f32_16x16x32_bf16(a, bb, acc0[nf], 0, 0, 0);
    }
  }

  // P = relu(acc0 + b_m1) -> LDS (fp32)
#pragma unroll
  for (int nf = 0; nf < 4; ++nf) {
    int colp = wn * 64 + nf * 16 + arow;
    float bb = b_m1[n0 + colp];
#pragma unroll
    for (int rr = 0; rr < 4; ++rr)
      Pl[wm * 16 + h * 4 + rr][colp] = fmaxf(acc0[nf][rr] + bb, 0.f);
  }
  __syncthreads();

  // stage 2: (32x128 P-tile) @ WmT[:, n0:n0+128]^T -> 32x128 partial of h
  f32x4 acc2[4];
#pragma unroll
  for (int nf = 0; nf < 4; ++nf) acc2[nf] = (f32x4){0.f, 0.f, 0.f, 0.f};
  const unsigned short* b2p[4];
#pragma unroll
  for (int nf = 0; nf < 4; ++nf)
    b2p[nf] = WmT + (size_t)(wn * 64 + nf * 16 + arow) * BNKD + n0 + ak;
  const float* prow = &Pl[wm * 16 + arow][0];

#pragma unroll
  for (int k2 = 0; k2 < 4; ++k2) {
    u16x8 uh, ul;
#pragma unroll
    for (int q = 0; q < 8; ++q) {
      float vv = prow[k2 * 32 + ak + q];
      unsigned short hh = f2bf(vv);
      uh[q] = hh;
      ul[q] = f2bf(vv - bf2f(hh));
    }
    bf16x8 ahi = __builtin_bit_cast(bf16x8, uh);
    bf16x8 alo = __builtin_bit_cast(bf16x8, ul);
#pragma unroll
    for (int nf = 0; nf < 4; ++nf) {
      bf16x8 bb = *(const bf16x8*)(b2p[nf] + k2 * 32);
      acc2[nf] = __builtin_amdgcn_mfma_f32_16x16x32_bf16(ahi, bb, acc2[nf], 0, 0, 0);
      acc2[nf] = __builtin_amdgcn_mfma_f32_16x16x32_bf16(alo, bb, acc2[nf], 0, 0, 0);
    }
  }
#pragma unroll
  for (int nf = 0; nf < 4; ++nf)
#pragma unroll
    for (int rr = 0; rr < 4; ++rr)
      atomicAdd(&hacc[(size_t)(r0 + wm * 16 + h * 4 + rr) * HD + wn * 64 + nf * 16 + arow],
                acc2[nf][rr]);
}

// ---------------------------------------------------------------------------
// final: h_fin = relu(hacc)
// ---------------------------------------------------------------------------
__global__ void final_h(const float* __restrict__ hacc, float* __restrict__ out) {
  int i = blockIdx.x * 256 + threadIdx.x;
  if (i < NB * HD) out[i] = fmaxf(hacc[i], 0.f);
}

// ---------------------------------------------------------------------------
extern "C" void kernel_launch(void* const* d_in, const int* in_sizes, int n_in,
                              void* d_out, int out_size, void* d_ws, size_t ws_size,
                              hipStream_t stream) {
  const float* last_pos     = (const float*)d_in[0];
  const float* last_pos_rel = (const float*)d_in[1];
  const float* h0   = (const float*)d_in[2];
  const float* c0   = (const float*)d_in[3];
  const float* W_se = (const float*)d_in[5];
  const float* b_se = (const float*)d_in[6];
  const float* W_ih = (const float*)d_in[7];
  const float* b_ih = (const float*)d_in[8];
  const float* W_hh = (const float*)d_in[9];
  const float* b_hh = (const float*)d_in[10];
  const float* W_hp = (const float*)d_in[11];
  const float* b_hp = (const float*)d_in[12];
  const float* W_pse = (const float*)d_in[13];
  const float* b_pse = (const float*)d_in[14];
  const float* W_p1 = (const float*)d_in[15];
  const float* b_p1 = (const float*)d_in[16];
  const float* W_p2 = (const float*)d_in[17];
  const float* b_p2 = (const float*)d_in[18];
  const float* W_m1 = (const float*)d_in[19];
  const float* b_m1 = (const float*)d_in[20];
  const float* W_m2 = (const float*)d_in[21];
  const float* b_m2 = (const float*)d_in[22];

  float* ws = (float*)d_ws;
  float* hacc[2]  = { ws,           ws + 98304 };
  float* ccar[2]  = { ws + 196608,  ws + 294912 };
  float* din[2]   = { ws + 393216,  ws + 442368 };
  float* lposb[2] = { ws + 491520,  ws + 493056 };
  float* Wc   = ws + 494592;                                // 1024
  float* bc   = ws + 495616;                                // 512
  unsigned short* W2T   = (unsigned short*)(ws + 496128);   // 1024x512 bf16
  unsigned short* W1T   = (unsigned short*)(ws + 758272);   // 1024x1152 bf16
  unsigned short* WmT   = (unsigned short*)(ws + 1348096);  // 128x1024 bf16
  unsigned short* mhA   = (unsigned short*)(ws + 1413632);  // 768x1152 bf16
  unsigned short* Wgbn  = (unsigned short*)(ws + 1856000);  // 512x192 bf16
  unsigned short* Wp1T2 = (unsigned short*)(ws + 1905152);  // 512x128 bf16

  float* pred = (float*)d_out;

  init_kernel<<<128, 256, 0, stream>>>(last_pos, last_pos_rel, c0,
                                       W_se, b_se, W_pse, b_pse, W_p1, b_p1,
                                       W_p2, W_m1, W_m2, W_ih, W_hh,
                                       ccar[0], din[0], lposb[0],
                                       Wc, bc, W2T, W1T, WmT, Wgbn, Wp1T2);

  for (int t = 0; t < TSTEPS; ++t) {
    int a = t & 1, b = (t + 1) & 1;
    step_a<<<384, 256, 0, stream>>>(
        t == 0 ? h0 : hacc[a], ccar[a], din[a],
        Wgbn, b_ih, b_hh, b_m2,
        mhA, ccar[b], hacc[b], t == 0 ? 0 : 1);
    pool_fused<<<NS * 8, 768, 0, stream>>>(
        lposb[a], Wc, bc, W2T, Wp1T2, b_p2, W_hp, b_hp, W_se, b_se,
        lposb[b], din[b], pred + t * NB * 2, mhA);
    mlp1_fused<<<192, 256, 0, stream>>>(mhA, W1T, b_m1, WmT, hacc[b]);
  }

  final_h<<<384, 256, 0, stream>>>(hacc[0], (float*)d_out + TSTEPS * NB * 2);
}